// Round 1
// baseline (104.846 us; speedup 1.0000x reference)
//
#include <hip/hip_runtime.h>

#define NB 32
#define NS 2048
#define NH 1024

// k1: v[b,h] = sum_d dec[b,d] * Wa[d,h]   (Wa row-major [d][h])
// grid = 4 h-tiles * 32 b, ordered so same-tile blocks are adjacent (L2 reuse)
__global__ __launch_bounds__(256) void k1_v(const float* __restrict__ dec,
                                            const float* __restrict__ Wa,
                                            float* __restrict__ v) {
    int htile = blockIdx.x >> 5;   // 0..3
    int b     = blockIdx.x & 31;   // 0..31
    int h = htile * 256 + threadIdx.x;
    const float* decb = dec + b * NH;
    float acc = 0.f;
#pragma unroll 8
    for (int d = 0; d < NH; ++d) {
        acc = fmaf(decb[d], Wa[d * NH + h], acc);   // decb[d] uniform -> s_load
    }
    v[b * NH + h] = acc;
}

// k2: scores[b,s] = enc[b,s,:] . v[b,:]
// 4 rows per block (all same b since 2048 % 4 == 0), one wave per row.
__global__ __launch_bounds__(256) void k2_scores(const float* __restrict__ enc,
                                                 const float* __restrict__ v,
                                                 float* __restrict__ scores) {
    __shared__ float vs[NH];
    int row0 = blockIdx.x * 4;
    int b = row0 >> 11;            // / NS
    // stage v[b] (4 KB) into LDS
    const float4* vsrc = (const float4*)(v + b * NH);
    ((float4*)vs)[threadIdx.x] = vsrc[threadIdx.x];
    __syncthreads();

    int wid  = threadIdx.x >> 6;
    int lane = threadIdx.x & 63;
    int row  = row0 + wid;
    const float4* e  = (const float4*)(enc + (size_t)row * NH);
    const float4* vv = (const float4*)vs;
    float acc = 0.f;
#pragma unroll
    for (int k = 0; k < 4; ++k) {
        float4 a  = e[k * 64 + lane];
        float4 bb = vv[k * 64 + lane];
        acc = fmaf(a.x, bb.x, acc);
        acc = fmaf(a.y, bb.y, acc);
        acc = fmaf(a.z, bb.z, acc);
        acc = fmaf(a.w, bb.w, acc);
    }
#pragma unroll
    for (int m = 32; m >= 1; m >>= 1) acc += __shfl_xor(acc, m, 64);
    if (lane == 0) scores[row] = acc;
}

// k3: per-b softmax stats, attn write (all S), windowed context.
// one block (256 threads) per b.
__global__ __launch_bounds__(256) void k3_final(const float* __restrict__ enc,
                                                const float* __restrict__ scores,
                                                const int* __restrict__ timestep,
                                                float* __restrict__ ctx,
                                                float* __restrict__ attn) {
    __shared__ float red[4];
    __shared__ float bm, bd;
    int b = blockIdx.x;
    int t = threadIdx.x;
    int wid = t >> 6, lane = t & 63;
    const float* sc = scores + b * NS;

    float s8[8];
#pragma unroll
    for (int k = 0; k < 8; ++k) s8[k] = sc[t + 256 * k];

    // ---- block max ----
    float m = s8[0];
#pragma unroll
    for (int k = 1; k < 8; ++k) m = fmaxf(m, s8[k]);
#pragma unroll
    for (int off = 32; off >= 1; off >>= 1) m = fmaxf(m, __shfl_xor(m, off, 64));
    if (lane == 0) red[wid] = m;
    __syncthreads();
    if (t == 0) bm = fmaxf(fmaxf(red[0], red[1]), fmaxf(red[2], red[3]));
    __syncthreads();
    m = bm;

    // ---- block sum of exp ----
    float sum = 0.f;
#pragma unroll
    for (int k = 0; k < 8; ++k) sum += expf(s8[k] - m);
#pragma unroll
    for (int off = 32; off >= 1; off >>= 1) sum += __shfl_xor(sum, off, 64);
    if (lane == 0) red[wid] = sum;
    __syncthreads();
    if (t == 0) bd = red[0] + red[1] + red[2] + red[3];
    __syncthreads();
    float inv = 1.0f / bd;

    // ---- attn = exp(score - m - 0.5 d^2) / denom  (== softmax * gaussian) ----
    float p = (float)timestep[b];
#pragma unroll
    for (int k = 0; k < 8; ++k) {
        int s = t + 256 * k;
        float d = (float)s - p;
        attn[b * NS + s] = expf(s8[k] - m - 0.5f * d * d) * inv;
    }

    // ---- context: only |s - p| <= 12 contributes (> 1e-30 cutoff) ----
    int pi = timestep[b];
    int s0 = max(0, pi - 12), s1 = min(NS - 1, pi + 12);
    float acc0 = 0.f, acc1 = 0.f, acc2 = 0.f, acc3 = 0.f;
    for (int s = s0; s <= s1; ++s) {
        float d = (float)s - p;
        float w = expf(sc[s] - m - 0.5f * d * d) * inv;
        const float* er = enc + ((size_t)b * NS + s) * NH;
        acc0 = fmaf(w, er[t], acc0);
        acc1 = fmaf(w, er[t + 256], acc1);
        acc2 = fmaf(w, er[t + 512], acc2);
        acc3 = fmaf(w, er[t + 768], acc3);
    }
    ctx[b * NH + t]       = acc0;
    ctx[b * NH + t + 256] = acc1;
    ctx[b * NH + t + 512] = acc2;
    ctx[b * NH + t + 768] = acc3;
}

extern "C" void kernel_launch(void* const* d_in, const int* in_sizes, int n_in,
                              void* d_out, int out_size, void* d_ws, size_t ws_size,
                              hipStream_t stream) {
    const float* enc  = (const float*)d_in[0];   // [B,S,H]
    const float* dec  = (const float*)d_in[1];   // [B,H]
    const int*   ts   = (const int*)d_in[2];     // [B]
    const float* Wa_w = (const float*)d_in[3];   // [H,H]
    // d_in[4] = Wa_b: constant per-b shift of scores -> softmax-invariant, dropped.

    float* out  = (float*)d_out;
    float* ctx  = out;             // [B,H]
    float* attn = out + NB * NH;   // [B,S]

    float* v      = (float*)d_ws;        // B*H floats
    float* scores = v + NB * NH;         // B*S floats

    k1_v     <<<128,            256, 0, stream>>>(dec, Wa_w, v);
    k2_scores<<<NB * NS / 4,    256, 0, stream>>>(enc, v, scores);
    k3_final <<<NB,             256, 0, stream>>>(enc, scores, ts, ctx, attn);
}